// Round 2
// baseline (1010.712 us; speedup 1.0000x reference)
//
#include <hip/hip_runtime.h>
#include <math.h>

#define NA 16
#define NS 64
#define NB 100
#define NE 12
#define ML 20
#define DD 512
#define NC (NA*NE)   /* 192 */
#define NR (NA*NS)   /* 1024 */
#define EPSF 1e-5f
#define DELTA_F 0.2f
#define PITCH 36     /* floats; 144B rows -> 16B aligned, bank stride 4 (2-way, free) */

// ---------- helpers ----------
__device__ inline void wave_minmax64(float v, float& mn, float& mx){
  mn = v; mx = v;
  #pragma unroll
  for (int off = 32; off > 0; off >>= 1){
    mn = fminf(mn, __shfl_xor(mn, off));
    mx = fmaxf(mx, __shfl_xor(mx, off));
  }
}

__device__ inline float wave_sum64(float v){
  #pragma unroll
  for (int off = 32; off > 0; off >>= 1) v += __shfl_xor(v, off);
  return v;
}

__device__ inline float block_sum256(float v, float* sred){
  int t = threadIdx.x;
  v = wave_sum64(v);
  if ((t & 63) == 0) sred[t >> 6] = v;
  __syncthreads();
  float tot = sred[0] + sred[1] + sred[2] + sred[3];
  __syncthreads();
  return tot;
}

// ---------- K1: fused GEMM + max/argmax over Nb ----------
// one block per r = a*NS+s. A-tile register-prefetched (double-buffered vs compute),
// LDS pitch 36 -> ds_read_b128 with immediate offsets in the 84-FMA inner loop.
__global__ __launch_bounds__(256) void k_gemm_max(
    const float* __restrict__ vis, const float* __restrict__ word,
    const int* __restrict__ elen, float* __restrict__ dind, float* __restrict__ dsim)
{
  __shared__ float As[112 * PITCH];   // rows 100..111 zeroed once
  __shared__ float Bs[NC * PITCH];
  const int r  = blockIdx.x;
  const int t  = threadIdx.x;
  const int tc = t & 15;          // col: c = jc*16+tc
  const int tb = t >> 4;          // row: b = tb*7+j

  float acc[7][12];
  #pragma unroll
  for (int j = 0; j < 7; ++j)
    #pragma unroll
    for (int jc = 0; jc < 12; ++jc) acc[j][jc] = 0.f;

  // zero pad rows (written once; staging only touches rows 0..99)
  for (int i = t; i < 12 * PITCH; i += 256) As[100 * PITCH + i] = 0.f;

  const float* abase = vis + (size_t)r * NB * DD;

  // prefetch A tile k0=0 into registers
  float4 pa[4];
  #pragma unroll
  for (int j = 0; j < 4; ++j){
    int i = t + 256 * j;
    if (i < NB * 8){ int b = i >> 3, q = i & 7;
      pa[j] = *(const float4*)(abase + (size_t)b * DD + q * 4); }
  }

  for (int k0 = 0; k0 < DD; k0 += 32){
    __syncthreads();   // previous compute done (WAR on LDS); also covers pad-zero init
    // A: registers -> LDS
    #pragma unroll
    for (int j = 0; j < 4; ++j){
      int i = t + 256 * j;
      if (i < NB * 8){ int b = i >> 3, q = i & 7;
        *(float4*)&As[b * PITCH + q * 4] = pa[j]; }
    }
    // B: global(L2) -> LDS
    #pragma unroll
    for (int j = 0; j < 6; ++j){
      int i = t + 256 * j;
      int c = i >> 3, q = i & 7;
      *(float4*)&Bs[c * PITCH + q * 4] = *(const float4*)(word + (size_t)c * DD + k0 + q * 4);
    }
    __syncthreads();
    // prefetch next A tile (overlaps with compute below)
    if (k0 + 32 < DD){
      #pragma unroll
      for (int j = 0; j < 4; ++j){
        int i = t + 256 * j;
        if (i < NB * 8){ int b = i >> 3, q = i & 7;
          pa[j] = *(const float4*)(abase + (size_t)b * DD + k0 + 32 + q * 4); }
      }
    }
    // compute: all LDS offsets are compile-time immediates off two bases
    #pragma unroll
    for (int kk = 0; kk < 32; kk += 4){
      float4 ar[7];
      #pragma unroll
      for (int j = 0; j < 7; ++j)
        ar[j] = *(const float4*)&As[(tb * 7 + j) * PITCH + kk];
      #pragma unroll
      for (int jc = 0; jc < 12; ++jc){
        float4 b4 = *(const float4*)&Bs[(jc * 16 + tc) * PITCH + kk];
        #pragma unroll
        for (int j = 0; j < 7; ++j){
          acc[j][jc] = fmaf(ar[j].x, b4.x, acc[j][jc]);
          acc[j][jc] = fmaf(ar[j].y, b4.y, acc[j][jc]);
          acc[j][jc] = fmaf(ar[j].z, b4.z, acc[j][jc]);
          acc[j][jc] = fmaf(ar[j].w, b4.w, acc[j][jc]);
        }
      }
    }
  }
  __syncthreads();   // all compute done before reusing As/Bs as scratch

  // ---- max/argmax over b ----
  float* redv = As;   // 192*16 = 3072 <= 4032
  float* redi = Bs;
  #pragma unroll
  for (int jc = 0; jc < 12; ++jc){
    int c = jc * 16 + tc;
    float best = -3.4e38f; int bi = 0;
    #pragma unroll
    for (int j = 0; j < 7; ++j){
      int b = tb * 7 + j;
      if (b < NB){ float v = acc[j][jc]; if (v > best){ best = v; bi = b; } }
    }
    redv[c * 16 + tb] = best;
    redi[c * 16 + tb] = (float)bi;
  }
  __syncthreads();
  if (t < NC){
    int c = t;
    float best = -3.4e38f; int bi = 0;
    #pragma unroll
    for (int g = 0; g < 16; ++g){          // ascending tb == ascending b -> first-index tie-break
      float v = redv[c * 16 + g];
      if (v > best){ best = v; bi = (int)redi[c * 16 + g]; }
    }
    int aw = c / NE, e = c - aw * NE;
    if (e >= elen[aw]){ best = 0.f; bi = 0; }
    dsim[r * NC + c] = best;
    dind[r * NC + c] = (float)bi;
  }
}

// ---------- K2: IoU ----------
__global__ __launch_bounds__(256) void k_iou(
    const float* __restrict__ boxes, const float* __restrict__ det, float* __restrict__ out)
{
  int idx = blockIdx.x * 256 + threadIdx.x;
  const int total = NA * NS * NB * ML;
  if (idx >= total) return;
  int m = idx % ML; int t2 = idx / ML; int b = t2 % NB; int t3 = t2 / NB;
  const float4 A = *(const float4*)(boxes + (size_t)(t3 * NB + b) * 4);
  int a = t3 / NS;
  const float4 B = *(const float4*)(det + (size_t)(a * ML + m) * 4);
  float iw = fminf(A.z, B.z) - fmaxf(A.x, B.x);
  float ih = fminf(A.w, B.w) - fmaxf(A.y, B.y);
  bool pos = (iw > 0.f) && (ih > 0.f);
  float inter = pos ? iw * ih : 0.f;
  float a1 = (A.z - A.x) * (A.w - A.y);
  float a2 = (B.z - B.x) * (B.w - B.y);
  float den = a1 + a2 - inter;
  out[idx] = pos ? inter / (den > 0.f ? den : 1.f) : 0.f;
}

// ---------- K3a: column-normalize D_sim over s, fold into Sf ----------
__global__ void k_sf(const float* __restrict__ dsim, const int* __restrict__ elen,
                     float* __restrict__ sf)
{
  int a = blockIdx.x, aw = blockIdx.y, s = threadIdx.x;
  float accv = 0.f;
  for (int e = 0; e < NE; ++e){
    int c = aw * NE + e;
    float v = dsim[(a * NS + s) * NC + c];
    float mn, mx; wave_minmax64(v, mn, mx);
    accv += v * (v - mn) / (mx - mn + EPSF);
  }
  float dv = fmaxf((float)elen[aw], 1.f);
  sf[(a * NS + s) * NA + aw] = accv / dv;
}

// ---------- K3b: normalize diagonal sim scores; zero accumulators ----------
__global__ void k_simnorm(const float* __restrict__ dsim, float* __restrict__ simn,
                          float* __restrict__ accums)
{
  int a = blockIdx.x, e = blockIdx.y, s = threadIdx.x;
  if (a == 0 && e == 0 && s == 0){ accums[0] = 0.f; accums[1] = 0.f; }
  float v = dsim[(a * NS + s) * NC + (a * NE + e)];
  float mn, mx; wave_minmax64(v, mn, mx);
  simn[(a * NS + s) * NE + e] = (v - mn) / (mx - mn + EPSF);
}

// ---------- K4a: per-(a,s,e) row norms -> inv table + nw2 atomic ----------
// one wave per triple; 3072 blocks x 4 waves
__global__ __launch_bounds__(256) void k_norms(
    const float* __restrict__ vis, const float* __restrict__ dind,
    const float* __restrict__ simn, const int* __restrict__ elen,
    float* __restrict__ invtab, float* __restrict__ accums)
{
  int idx = blockIdx.x * 4 + (threadIdx.x >> 6);
  int lane = threadIdx.x & 63;
  int e = idx % NE; int rs = idx / NE; int a = rs >> 6;
  int mi = (int)dind[(size_t)rs * NC + a * NE + e];
  const float* row = vis + ((size_t)rs * NB + mi) * DD;
  float ss = 0.f;
  #pragma unroll
  for (int q = 0; q < 8; ++q){ float x = row[lane + 64 * q]; ss = fmaf(x, x, ss); }
  ss = wave_sum64(ss);
  if (lane == 0){
    float sn = simn[idx];
    float inv = sn / (sqrtf(ss) + EPSF);
    invtab[idx] = inv;
    if (e < elen[a]) atomicAdd(&accums[0], inv * inv * ss);   // sum_s ||w_s||^2
  }
}

// ---------- K4b: W accumulation per valid (a,e), barrier-free s-loop ----------
__global__ __launch_bounds__(256) void k_gram2(
    const float* __restrict__ vis, const float* __restrict__ dind,
    const float* __restrict__ invtab, const int* __restrict__ elen,
    float* __restrict__ accums)
{
  int a = blockIdx.x / NE, e = blockIdx.x % NE;
  if (e >= elen[a]) return;
  __shared__ float sred[4];
  int t = threadIdx.x;
  float W0 = 0.f, W1 = 0.f;
  #pragma unroll 4
  for (int s = 0; s < NS; ++s){
    int rs = a * NS + s;
    float inv = invtab[(size_t)rs * NE + e];
    int mi = (int)dind[(size_t)rs * NC + a * NE + e];
    const float* row = vis + ((size_t)rs * NB + mi) * DD;
    W0 = fmaf(row[t], inv, W0);
    W1 = fmaf(row[t + 256], inv, W1);
  }
  float w2 = block_sum256(W0 * W0 + W1 * W1, sred);
  if (t == 0){
    atomicAdd(&accums[0], (float)(NS * (NS - 1)) - w2);
    atomicAdd(&accums[1], (float)(NS * (NS - 1)));
  }
}

// ---------- K5: Sf margin terms + final loss ----------
__global__ __launch_bounds__(256) void k_final(
    const float* __restrict__ sf, const float* __restrict__ accums, float* __restrict__ out)
{
  __shared__ float sred[4];
  int t = threadIdx.x;
  float sum = 0.f;
  for (int i = t; i < NA * NS * NA; i += 256){
    int b = i & (NA - 1);
    int s = (i >> 4) & (NS - 1);
    int a = i >> 10;
    float v  = sf[i];
    float d1 = sf[(b * NS + s) * NA + b];
    float d2 = sf[(a * NS + s) * NA + a];
    sum += fmaxf(v - d1 + DELTA_F, 0.f) + fmaxf(v - d2 + DELTA_F, 0.f);
  }
  float tot = block_sum256(sum, sred);
  if (t == 0){
    float frame = tot / (float)(NA * NA * NS);
    float cnt = accums[1];
    float vis_loss = accums[0] / fmaxf(cnt, 1.f);
    out[0] = (frame + vis_loss) * 10.f;
  }
}

// ---------- launch ----------
extern "C" void kernel_launch(void* const* d_in, const int* in_sizes, int n_in,
                              void* d_out, int out_size, void* d_ws, size_t ws_size,
                              hipStream_t stream)
{
  const float* vis   = (const float*)d_in[0];
  const float* word  = (const float*)d_in[1];
  const float* boxes = (const float*)d_in[2];
  const float* det   = (const float*)d_in[3];
  const int*   elen  = (const int*)d_in[4];

  float* out   = (float*)d_out;
  float* dind  = out;
  float* dsim  = out + NR * NC;
  float* mloss = out + 2 * NR * NC;
  float* dtin  = mloss + 1;

  float* ws     = (float*)d_ws;
  float* sf     = ws;                         // 16384
  float* simn   = ws + NA * NS * NA;          // 12288
  float* accums = simn + NA * NS * NE;        // 16 (2 used)
  float* invtab = accums + 16;                // 12288

  k_gemm_max<<<NR, 256, 0, stream>>>(vis, word, elen, dind, dsim);
  k_iou<<<(NA * NS * NB * ML + 255) / 256, 256, 0, stream>>>(boxes, det, dtin);
  k_sf<<<dim3(NA, NA), 64, 0, stream>>>(dsim, elen, sf);
  k_simnorm<<<dim3(NA, NE), 64, 0, stream>>>(dsim, simn, accums);
  k_norms<<<(NA * NS * NE) / 4, 256, 0, stream>>>(vis, dind, simn, elen, invtab, accums);
  k_gram2<<<NA * NE, 256, 0, stream>>>(vis, dind, invtab, elen, accums);
  k_final<<<1, 256, 0, stream>>>(sf, accums, mloss);
}

// Round 3
// 873.231 us; speedup vs baseline: 1.1574x; 1.1574x over previous
//
#include <hip/hip_runtime.h>
#include <math.h>

#define NA 16
#define NS 64
#define NB 100
#define NE 12
#define ML 20
#define DD 512
#define NC (NA*NE)   /* 192 */
#define NR (NA*NS)   /* 1024 */
#define EPSF 1e-5f
#define DELTA_F 0.2f
#define PITCHB 36    /* 144B rows: 16B-aligned (b128 ok), bank stride 4 -> 2-way only (free) */

// ---------- helpers ----------
__device__ inline void wave_minmax64(float v, float& mn, float& mx){
  mn = v; mx = v;
  #pragma unroll
  for (int off = 32; off > 0; off >>= 1){
    mn = fminf(mn, __shfl_xor(mn, off));
    mx = fmaxf(mx, __shfl_xor(mx, off));
  }
}

__device__ inline float wave_sum64(float v){
  #pragma unroll
  for (int off = 32; off > 0; off >>= 1) v += __shfl_xor(v, off);
  return v;
}

__device__ inline float block_sum256(float v, float* sred){
  int t = threadIdx.x;
  v = wave_sum64(v);
  if ((t & 63) == 0) sred[t >> 6] = v;
  __syncthreads();
  float tot = sred[0] + sred[1] + sred[2] + sred[3];
  __syncthreads();
  return tot;
}

// ---------- K1: fused GEMM + max/argmax over Nb ----------
// One block per r. A read DIRECT from global (4 distinct addrs/wave, broadcast, L1-resident
// 12.8KB tile) -> VMEM pipe. B staged in LDS pitch-36 -> 12 ds_read_b128 per 336 FMA.
__global__ __launch_bounds__(256) void k_gemm_max(
    const float* __restrict__ vis, const float* __restrict__ word,
    const int* __restrict__ elen, float* __restrict__ dind, float* __restrict__ dsim)
{
  __shared__ float Bs[NC * PITCHB];   // 6912 floats = 27.6 KB
  const int r  = blockIdx.x;
  const int t  = threadIdx.x;
  const int tc = t & 15;          // col: c = jc*16+tc
  const int tb = t >> 4;          // row: b = tb*7+j

  float acc[7][12];
  #pragma unroll
  for (int j = 0; j < 7; ++j)
    #pragma unroll
    for (int jc = 0; jc < 12; ++jc) acc[j][jc] = 0.f;

  const float* abase = vis + (size_t)r * NB * DD;
  int rowoff[7];
  #pragma unroll
  for (int j = 0; j < 7; ++j){
    int b = tb * 7 + j; b = (b < NB) ? b : (NB - 1);   // clamped dup rows; masked in epilogue
    rowoff[j] = b * DD;
  }

  for (int k0 = 0; k0 < DD; k0 += 32){
    __syncthreads();   // WAR on Bs
    #pragma unroll
    for (int jj = 0; jj < 6; ++jj){
      int i = t + 256 * jj;
      int c = i >> 3, q = i & 7;
      *(float4*)&Bs[c * PITCHB + q * 4] = *(const float4*)(word + (size_t)c * DD + k0 + q * 4);
    }
    __syncthreads();
    #pragma unroll 2
    for (int g = 0; g < 8; ++g){
      float4 ar[7];
      #pragma unroll
      for (int j = 0; j < 7; ++j)
        ar[j] = *(const float4*)(abase + rowoff[j] + k0 + g * 4);
      #pragma unroll
      for (int jc = 0; jc < 12; ++jc){
        float4 b4 = *(const float4*)&Bs[(jc * 16 + tc) * PITCHB + g * 4];
        #pragma unroll
        for (int j = 0; j < 7; ++j){
          acc[j][jc] = fmaf(ar[j].x, b4.x, acc[j][jc]);
          acc[j][jc] = fmaf(ar[j].y, b4.y, acc[j][jc]);
          acc[j][jc] = fmaf(ar[j].z, b4.z, acc[j][jc]);
          acc[j][jc] = fmaf(ar[j].w, b4.w, acc[j][jc]);
        }
      }
    }
  }
  __syncthreads();   // compute done before reusing Bs as scratch

  // ---- max/argmax over b ----
  float* redv = Bs;             // 3072
  float* redi = Bs + NC * 16;   // 3072 (total 6144 <= 6912)
  #pragma unroll
  for (int jc = 0; jc < 12; ++jc){
    int c = jc * 16 + tc;
    float best = -3.4e38f; int bi = 0;
    #pragma unroll
    for (int j = 0; j < 7; ++j){
      int b = tb * 7 + j;
      if (b < NB){ float v = acc[j][jc]; if (v > best){ best = v; bi = b; } }
    }
    redv[c * 16 + tb] = best;
    redi[c * 16 + tb] = (float)bi;
  }
  __syncthreads();
  if (t < NC){
    int c = t;
    float best = -3.4e38f; int bi = 0;
    #pragma unroll
    for (int g = 0; g < 16; ++g){          // ascending tb == ascending b -> first-index tie-break
      float v = redv[c * 16 + g];
      if (v > best){ best = v; bi = (int)redi[c * 16 + g]; }
    }
    int aw = c / NE, e = c - aw * NE;
    if (e >= elen[aw]){ best = 0.f; bi = 0; }
    dsim[r * NC + c] = best;
    dind[r * NC + c] = (float)bi;
  }
}

// ---------- K2: IoU ----------
__global__ __launch_bounds__(256) void k_iou(
    const float* __restrict__ boxes, const float* __restrict__ det, float* __restrict__ out)
{
  int idx = blockIdx.x * 256 + threadIdx.x;
  const int total = NA * NS * NB * ML;
  if (idx >= total) return;
  int m = idx % ML; int t2 = idx / ML; int b = t2 % NB; int t3 = t2 / NB;
  const float4 A = *(const float4*)(boxes + (size_t)(t3 * NB + b) * 4);
  int a = t3 / NS;
  const float4 B = *(const float4*)(det + (size_t)(a * ML + m) * 4);
  float iw = fminf(A.z, B.z) - fmaxf(A.x, B.x);
  float ih = fminf(A.w, B.w) - fmaxf(A.y, B.y);
  bool pos = (iw > 0.f) && (ih > 0.f);
  float inter = pos ? iw * ih : 0.f;
  float a1 = (A.z - A.x) * (A.w - A.y);
  float a2 = (B.z - B.x) * (B.w - B.y);
  float den = a1 + a2 - inter;
  out[idx] = pos ? inter / (den > 0.f ? den : 1.f) : 0.f;
}

// ---------- K3a: column-normalize D_sim over s, fold into Sf ----------
__global__ void k_sf(const float* __restrict__ dsim, const int* __restrict__ elen,
                     float* __restrict__ sf)
{
  int a = blockIdx.x, aw = blockIdx.y, s = threadIdx.x;
  float accv = 0.f;
  for (int e = 0; e < NE; ++e){
    int c = aw * NE + e;
    float v = dsim[(a * NS + s) * NC + c];
    float mn, mx; wave_minmax64(v, mn, mx);
    accv += v * (v - mn) / (mx - mn + EPSF);
  }
  float dv = fmaxf((float)elen[aw], 1.f);
  sf[(a * NS + s) * NA + aw] = accv / dv;
}

// ---------- K3b: normalize diagonal sim scores; zero accumulators ----------
__global__ void k_simnorm(const float* __restrict__ dsim, float* __restrict__ simn,
                          float* __restrict__ accums)
{
  int a = blockIdx.x, e = blockIdx.y, s = threadIdx.x;
  if (a == 0 && e == 0 && s == 0){ accums[0] = 0.f; accums[1] = 0.f; }
  float v = dsim[(a * NS + s) * NC + (a * NE + e)];
  float mn, mx; wave_minmax64(v, mn, mx);
  simn[(a * NS + s) * NE + e] = (v - mn) / (mx - mn + EPSF);
}

// ---------- K4a: per-(a,s,e) row norms -> inv table + nw2 atomic ----------
__global__ __launch_bounds__(256) void k_norms(
    const float* __restrict__ vis, const float* __restrict__ dind,
    const float* __restrict__ simn, const int* __restrict__ elen,
    float* __restrict__ invtab, float* __restrict__ accums)
{
  int idx = blockIdx.x * 4 + (threadIdx.x >> 6);
  int lane = threadIdx.x & 63;
  int e = idx % NE; int rs = idx / NE; int a = rs >> 6;
  int mi = (int)dind[(size_t)rs * NC + a * NE + e];
  const float* row = vis + ((size_t)rs * NB + mi) * DD;
  float ss = 0.f;
  #pragma unroll
  for (int q = 0; q < 8; ++q){ float x = row[lane + 64 * q]; ss = fmaf(x, x, ss); }
  ss = wave_sum64(ss);
  if (lane == 0){
    float sn = simn[idx];
    float inv = sn / (sqrtf(ss) + EPSF);
    invtab[idx] = inv;
    if (e < elen[a]) atomicAdd(&accums[0], inv * inv * ss);   // sum_s ||w_s||^2
  }
}

// ---------- K4b: W accumulation per valid (a,e), barrier-free s-loop ----------
__global__ __launch_bounds__(256) void k_gram2(
    const float* __restrict__ vis, const float* __restrict__ dind,
    const float* __restrict__ invtab, const int* __restrict__ elen,
    float* __restrict__ accums)
{
  int a = blockIdx.x / NE, e = blockIdx.x % NE;
  if (e >= elen[a]) return;
  __shared__ float sred[4];
  int t = threadIdx.x;
  float W0 = 0.f, W1 = 0.f;
  #pragma unroll 4
  for (int s = 0; s < NS; ++s){
    int rs = a * NS + s;
    float inv = invtab[(size_t)rs * NE + e];
    int mi = (int)dind[(size_t)rs * NC + a * NE + e];
    const float* row = vis + ((size_t)rs * NB + mi) * DD;
    W0 = fmaf(row[t], inv, W0);
    W1 = fmaf(row[t + 256], inv, W1);
  }
  float w2 = block_sum256(W0 * W0 + W1 * W1, sred);
  if (t == 0){
    atomicAdd(&accums[0], (float)(NS * (NS - 1)) - w2);
    atomicAdd(&accums[1], (float)(NS * (NS - 1)));
  }
}

// ---------- K5: Sf margin terms + final loss ----------
__global__ __launch_bounds__(256) void k_final(
    const float* __restrict__ sf, const float* __restrict__ accums, float* __restrict__ out)
{
  __shared__ float sred[4];
  int t = threadIdx.x;
  float sum = 0.f;
  for (int i = t; i < NA * NS * NA; i += 256){
    int b = i & (NA - 1);
    int s = (i >> 4) & (NS - 1);
    int a = i >> 10;
    float v  = sf[i];
    float d1 = sf[(b * NS + s) * NA + b];
    float d2 = sf[(a * NS + s) * NA + a];
    sum += fmaxf(v - d1 + DELTA_F, 0.f) + fmaxf(v - d2 + DELTA_F, 0.f);
  }
  float tot = block_sum256(sum, sred);
  if (t == 0){
    float frame = tot / (float)(NA * NA * NS);
    float cnt = accums[1];
    float vis_loss = accums[0] / fmaxf(cnt, 1.f);
    out[0] = (frame + vis_loss) * 10.f;
  }
}

// ---------- launch ----------
extern "C" void kernel_launch(void* const* d_in, const int* in_sizes, int n_in,
                              void* d_out, int out_size, void* d_ws, size_t ws_size,
                              hipStream_t stream)
{
  const float* vis   = (const float*)d_in[0];
  const float* word  = (const float*)d_in[1];
  const float* boxes = (const float*)d_in[2];
  const float* det   = (const float*)d_in[3];
  const int*   elen  = (const int*)d_in[4];

  float* out   = (float*)d_out;
  float* dind  = out;
  float* dsim  = out + NR * NC;
  float* mloss = out + 2 * NR * NC;
  float* dtin  = mloss + 1;

  float* ws     = (float*)d_ws;
  float* sf     = ws;                         // 16384
  float* simn   = ws + NA * NS * NA;          // 12288
  float* accums = simn + NA * NS * NE;        // 16 (2 used)
  float* invtab = accums + 16;                // 12288

  k_gemm_max<<<NR, 256, 0, stream>>>(vis, word, elen, dind, dsim);
  k_iou<<<(NA * NS * NB * ML + 255) / 256, 256, 0, stream>>>(boxes, det, dtin);
  k_sf<<<dim3(NA, NA), 64, 0, stream>>>(dsim, elen, sf);
  k_simnorm<<<dim3(NA, NE), 64, 0, stream>>>(dsim, simn, accums);
  k_norms<<<(NA * NS * NE) / 4, 256, 0, stream>>>(vis, dind, simn, elen, invtab, accums);
  k_gram2<<<NA * NE, 256, 0, stream>>>(vis, dind, invtab, elen, accums);
  k_final<<<1, 256, 0, stream>>>(sf, accums, mloss);
}

// Round 4
// 731.383 us; speedup vs baseline: 1.3819x; 1.1939x over previous
//
#include <hip/hip_runtime.h>
#include <math.h>

#define NA 16
#define NS 64
#define NB 100
#define NE 12
#define ML 20
#define DD 512
#define NC (NA*NE)   /* 192 */
#define NR (NA*NS)   /* 1024 */
#define EPSF 1e-5f
#define DELTA_F 0.2f

typedef short short8 __attribute__((ext_vector_type(8)));   // 8 bf16 (4 VGPRs)
typedef float f32x16 __attribute__((ext_vector_type(16)));  // 32x32 acc (16 AGPRs)

// ---------- helpers ----------
__device__ inline void wave_minmax64(float v, float& mn, float& mx){
  mn = v; mx = v;
  #pragma unroll
  for (int off = 32; off > 0; off >>= 1){
    mn = fminf(mn, __shfl_xor(mn, off));
    mx = fmaxf(mx, __shfl_xor(mx, off));
  }
}

__device__ inline float wave_sum64(float v){
  #pragma unroll
  for (int off = 32; off > 0; off >>= 1) v += __shfl_xor(v, off);
  return v;
}

__device__ inline float block_sum256(float v, float* sred){
  int t = threadIdx.x;
  v = wave_sum64(v);
  if ((t & 63) == 0) sred[t >> 6] = v;
  __syncthreads();
  float tot = sred[0] + sred[1] + sred[2] + sred[3];
  __syncthreads();
  return tot;
}

// split-3: x = h + m + l, each a truncated bf16; subtractions exact (Sterbenz)
__device__ inline void split3(float x, short& h, short& m, short& l){
  unsigned u = __float_as_uint(x);
  h = (short)(u >> 16);
  float r1 = x - __uint_as_float(u & 0xffff0000u);
  unsigned u1 = __float_as_uint(r1);
  m = (short)(u1 >> 16);
  float r2 = r1 - __uint_as_float(u1 & 0xffff0000u);
  l = (short)(__float_as_uint(r2) >> 16);
}

// ---------- K0: pre-split word feats into 3 bf16 planes ----------
__global__ __launch_bounds__(256) void k_split_b(
    const float* __restrict__ word, short* __restrict__ wh,
    short* __restrict__ wm, short* __restrict__ wl)
{
  int i = blockIdx.x * 256 + threadIdx.x;   // NC*DD = 98304 total
  float x = word[i];
  short h, m, l; split3(x, h, m, l);
  wh[i] = h; wm[i] = m; wl[i] = l;
}

// ---------- K1: MFMA split-3 GEMM + max/argmax over Nb ----------
// block per r (1024). wave w: rows b in [32w,32w+32) x all 192 cols (6 tiles of 32).
// A streamed from global fp32 + split in VALU; B from pre-split bf16 planes (L1/L2).
__global__ __launch_bounds__(256) void k_gemm_max(
    const float* __restrict__ vis,
    const short* __restrict__ wh, const short* __restrict__ wm, const short* __restrict__ wl,
    const int* __restrict__ elen, float* __restrict__ dind, float* __restrict__ dsim)
{
  __shared__ float redv[4][NC];
  __shared__ float redi[4][NC];
  const int r = blockIdx.x, t = threadIdx.x;
  const int w = t >> 6, lane = t & 63;
  const int mrow = lane & 31;          // row within 32x32 tile (A) / col within tile (B,C)
  const int kg = lane >> 5;            // k subgroup: k = kg*8 + j

  int b = w * 32 + mrow;
  int bc = (b < NB) ? b : (NB - 1);    // clamp pad rows (excluded in reduction)
  const float* ap = vis + ((size_t)r * NB + bc) * DD + kg * 8;
  const int boff = mrow * DD + kg * 8;

  f32x16 acc[6];
  #pragma unroll
  for (int nt = 0; nt < 6; ++nt)
    #pragma unroll
    for (int j = 0; j < 16; ++j) acc[nt][j] = 0.f;

  #pragma unroll 2
  for (int k0 = 0; k0 < DD; k0 += 16){
    // A: 8 fp32 -> 3 bf16 fragments
    float4 a0 = *(const float4*)(ap + k0);
    float4 a1 = *(const float4*)(ap + k0 + 4);
    float av[8] = {a0.x, a0.y, a0.z, a0.w, a1.x, a1.y, a1.z, a1.w};
    short8 ah, am2, al2;
    #pragma unroll
    for (int j = 0; j < 8; ++j){
      short h, m, l; split3(av[j], h, m, l);
      ah[j] = h; am2[j] = m; al2[j] = l;
    }
    #pragma unroll
    for (int nt = 0; nt < 6; ++nt){
      int off = nt * 32 * DD + boff + k0;
      short8 bh = *(const short8*)(wh + off);
      short8 bm = *(const short8*)(wm + off);
      short8 bl = *(const short8*)(wl + off);
      acc[nt] = __builtin_amdgcn_mfma_f32_32x32x16_bf16(ah,  bh, acc[nt], 0, 0, 0);
      acc[nt] = __builtin_amdgcn_mfma_f32_32x32x16_bf16(am2, bh, acc[nt], 0, 0, 0);
      acc[nt] = __builtin_amdgcn_mfma_f32_32x32x16_bf16(al2, bh, acc[nt], 0, 0, 0);
      acc[nt] = __builtin_amdgcn_mfma_f32_32x32x16_bf16(ah,  bm, acc[nt], 0, 0, 0);
      acc[nt] = __builtin_amdgcn_mfma_f32_32x32x16_bf16(am2, bm, acc[nt], 0, 0, 0);
      acc[nt] = __builtin_amdgcn_mfma_f32_32x32x16_bf16(ah,  bl, acc[nt], 0, 0, 0);
    }
  }

  // ---- per-lane max/argmax over this wave's 32 rows ----
  // C/D layout 32x32: col = lane&31, row = (reg&3) + 4*(lane>>5) + 8*(reg>>2)
  float best[6]; int bi[6];
  #pragma unroll
  for (int nt = 0; nt < 6; ++nt){ best[nt] = -3.4e38f; bi[nt] = 0; }
  #pragma unroll
  for (int reg = 0; reg < 16; ++reg){
    int bidx = w * 32 + (reg & 3) + 4 * kg + 8 * (reg >> 2);
    bool ok = bidx < NB;
    #pragma unroll
    for (int nt = 0; nt < 6; ++nt){
      float v = acc[nt][reg];
      if (ok && (v > best[nt] || (v == best[nt] && bidx < bi[nt]))){ best[nt] = v; bi[nt] = bidx; }
    }
  }
  #pragma unroll
  for (int nt = 0; nt < 6; ++nt){   // merge the two k-groups (same col, different rows)
    float ov = __shfl_xor(best[nt], 32);
    int   oi = __shfl_xor(bi[nt], 32);
    if (ov > best[nt] || (ov == best[nt] && oi < bi[nt])){ best[nt] = ov; bi[nt] = oi; }
  }
  if (kg == 0){
    #pragma unroll
    for (int nt = 0; nt < 6; ++nt){
      int c = nt * 32 + mrow;
      redv[w][c] = best[nt];
      redi[w][c] = (float)bi[nt];
    }
  }
  __syncthreads();
  if (t < NC){
    float bb = -3.4e38f; int bbi = 0;
    #pragma unroll
    for (int w2 = 0; w2 < 4; ++w2){      // ascending w2 == ascending b
      float v = redv[w2][t]; int i2 = (int)redi[w2][t];
      if (v > bb || (v == bb && i2 < bbi)){ bb = v; bbi = i2; }
    }
    int aw = t / NE, e = t - aw * NE;
    if (e >= elen[aw]){ bb = 0.f; bbi = 0; }   // masked col: S_=0 -> max 0, argmax 0
    dsim[r * NC + t] = bb;
    dind[r * NC + t] = (float)bbi;
  }
}

// ---------- K2: IoU ----------
__global__ __launch_bounds__(256) void k_iou(
    const float* __restrict__ boxes, const float* __restrict__ det, float* __restrict__ out)
{
  int idx = blockIdx.x * 256 + threadIdx.x;
  const int total = NA * NS * NB * ML;
  if (idx >= total) return;
  int m = idx % ML; int t2 = idx / ML; int b = t2 % NB; int t3 = t2 / NB;
  const float4 A = *(const float4*)(boxes + (size_t)(t3 * NB + b) * 4);
  int a = t3 / NS;
  const float4 B = *(const float4*)(det + (size_t)(a * ML + m) * 4);
  float iw = fminf(A.z, B.z) - fmaxf(A.x, B.x);
  float ih = fminf(A.w, B.w) - fmaxf(A.y, B.y);
  bool pos = (iw > 0.f) && (ih > 0.f);
  float inter = pos ? iw * ih : 0.f;
  float a1 = (A.z - A.x) * (A.w - A.y);
  float a2 = (B.z - B.x) * (B.w - B.y);
  float den = a1 + a2 - inter;
  out[idx] = pos ? inter / (den > 0.f ? den : 1.f) : 0.f;
}

// ---------- K3a: column-normalize D_sim over s, fold into Sf ----------
__global__ void k_sf(const float* __restrict__ dsim, const int* __restrict__ elen,
                     float* __restrict__ sf)
{
  int a = blockIdx.x, aw = blockIdx.y, s = threadIdx.x;
  float accv = 0.f;
  for (int e = 0; e < NE; ++e){
    int c = aw * NE + e;
    float v = dsim[(a * NS + s) * NC + c];
    float mn, mx; wave_minmax64(v, mn, mx);
    accv += v * (v - mn) / (mx - mn + EPSF);
  }
  float dv = fmaxf((float)elen[aw], 1.f);
  sf[(a * NS + s) * NA + aw] = accv / dv;
}

// ---------- K3b: normalize diagonal sim scores; zero accumulators ----------
__global__ void k_simnorm(const float* __restrict__ dsim, float* __restrict__ simn,
                          float* __restrict__ accums)
{
  int a = blockIdx.x, e = blockIdx.y, s = threadIdx.x;
  if (a == 0 && e == 0 && s == 0){ accums[0] = 0.f; accums[1] = 0.f; }
  float v = dsim[(a * NS + s) * NC + (a * NE + e)];
  float mn, mx; wave_minmax64(v, mn, mx);
  simn[(a * NS + s) * NE + e] = (v - mn) / (mx - mn + EPSF);
}

// ---------- K4a: per-(a,s,e) row norms -> inv table + nw2 atomic ----------
__global__ __launch_bounds__(256) void k_norms(
    const float* __restrict__ vis, const float* __restrict__ dind,
    const float* __restrict__ simn, const int* __restrict__ elen,
    float* __restrict__ invtab, float* __restrict__ accums)
{
  int idx = blockIdx.x * 4 + (threadIdx.x >> 6);
  int lane = threadIdx.x & 63;
  int e = idx % NE; int rs = idx / NE; int a = rs >> 6;
  int mi = (int)dind[(size_t)rs * NC + a * NE + e];
  const float* row = vis + ((size_t)rs * NB + mi) * DD;
  float ss = 0.f;
  #pragma unroll
  for (int q = 0; q < 8; ++q){ float x = row[lane + 64 * q]; ss = fmaf(x, x, ss); }
  ss = wave_sum64(ss);
  if (lane == 0){
    float sn = simn[idx];
    float inv = sn / (sqrtf(ss) + EPSF);
    invtab[idx] = inv;
    if (e < elen[a]) atomicAdd(&accums[0], inv * inv * ss);   // sum_s ||w_s||^2
  }
}

// ---------- K4b: W accumulation per valid (a,e), barrier-free s-loop ----------
__global__ __launch_bounds__(256) void k_gram2(
    const float* __restrict__ vis, const float* __restrict__ dind,
    const float* __restrict__ invtab, const int* __restrict__ elen,
    float* __restrict__ accums)
{
  int a = blockIdx.x / NE, e = blockIdx.x % NE;
  if (e >= elen[a]) return;
  __shared__ float sred[4];
  int t = threadIdx.x;
  float W0 = 0.f, W1 = 0.f;
  #pragma unroll 4
  for (int s = 0; s < NS; ++s){
    int rs = a * NS + s;
    float inv = invtab[(size_t)rs * NE + e];
    int mi = (int)dind[(size_t)rs * NC + a * NE + e];
    const float* row = vis + ((size_t)rs * NB + mi) * DD;
    W0 = fmaf(row[t], inv, W0);
    W1 = fmaf(row[t + 256], inv, W1);
  }
  float w2 = block_sum256(W0 * W0 + W1 * W1, sred);
  if (t == 0){
    atomicAdd(&accums[0], (float)(NS * (NS - 1)) - w2);
    atomicAdd(&accums[1], (float)(NS * (NS - 1)));
  }
}

// ---------- K5: Sf margin terms + final loss ----------
__global__ __launch_bounds__(256) void k_final(
    const float* __restrict__ sf, const float* __restrict__ accums, float* __restrict__ out)
{
  __shared__ float sred[4];
  int t = threadIdx.x;
  float sum = 0.f;
  for (int i = t; i < NA * NS * NA; i += 256){
    int b = i & (NA - 1);
    int s = (i >> 4) & (NS - 1);
    int a = i >> 10;
    float v  = sf[i];
    float d1 = sf[(b * NS + s) * NA + b];
    float d2 = sf[(a * NS + s) * NA + a];
    sum += fmaxf(v - d1 + DELTA_F, 0.f) + fmaxf(v - d2 + DELTA_F, 0.f);
  }
  float tot = block_sum256(sum, sred);
  if (t == 0){
    float frame = tot / (float)(NA * NA * NS);
    float cnt = accums[1];
    float vis_loss = accums[0] / fmaxf(cnt, 1.f);
    out[0] = (frame + vis_loss) * 10.f;
  }
}

// ---------- launch ----------
extern "C" void kernel_launch(void* const* d_in, const int* in_sizes, int n_in,
                              void* d_out, int out_size, void* d_ws, size_t ws_size,
                              hipStream_t stream)
{
  const float* vis   = (const float*)d_in[0];
  const float* word  = (const float*)d_in[1];
  const float* boxes = (const float*)d_in[2];
  const float* det   = (const float*)d_in[3];
  const int*   elen  = (const int*)d_in[4];

  float* out   = (float*)d_out;
  float* dind  = out;
  float* dsim  = out + NR * NC;
  float* mloss = out + 2 * NR * NC;
  float* dtin  = mloss + 1;

  float* ws     = (float*)d_ws;
  float* sf     = ws;                         // 16384 f
  float* simn   = ws + NA * NS * NA;          // 12288 f
  float* accums = simn + NA * NS * NE;        // 16 f (2 used)
  float* invtab = accums + 16;                // 12288 f
  short* wh     = (short*)(invtab + NA * NS * NE);   // 98304 shorts each, 16B-aligned
  short* wm     = wh + NC * DD;
  short* wl     = wm + NC * DD;

  k_split_b<<<NC * DD / 256, 256, 0, stream>>>(word, wh, wm, wl);
  k_gemm_max<<<NR, 256, 0, stream>>>(vis, wh, wm, wl, elen, dind, dsim);
  k_iou<<<(NA * NS * NB * ML + 255) / 256, 256, 0, stream>>>(boxes, det, dtin);
  k_sf<<<dim3(NA, NA), 64, 0, stream>>>(dsim, elen, sf);
  k_simnorm<<<dim3(NA, NE), 64, 0, stream>>>(dsim, simn, accums);
  k_norms<<<(NA * NS * NE) / 4, 256, 0, stream>>>(vis, dind, simn, elen, invtab, accums);
  k_gram2<<<NA * NE, 256, 0, stream>>>(vis, dind, invtab, elen, accums);
  k_final<<<1, 256, 0, stream>>>(sf, accums, mloss);
}